// Round 7
// baseline (173.637 us; speedup 1.0000x reference)
//
#include <hip/hip_runtime.h>

typedef _Float16 half_t;
typedef _Float16 half8 __attribute__((ext_vector_type(8)));
typedef _Float16 half4v __attribute__((ext_vector_type(4)));
typedef float f32x4 __attribute__((ext_vector_type(4)));
typedef float f32x2 __attribute__((ext_vector_type(2)));

#define NB 2
#define NN 8192
#define ND 512
#define NKNN 16
#define BN (NB*NN)

// ---------------- workspace layout (bytes, all 256-aligned) ----------------
#define OFF_XH   0ull                                 // x in fp16        16.8 MB
#define OFF_VH   (OFF_XH  + (size_t)BN*ND*2)          // v in fp16        16.8 MB
#define OFF_XOH  (OFF_VH  + (size_t)BN*ND*2)          // x_out in fp16    16.8 MB
#define OFF_WVH  (OFF_XOH + (size_t)BN*ND*2)          // W_v fp16         512 KB
#define OFF_WFCH (OFF_WVH + (size_t)ND*ND*2)          // W_fc fp16        512 KB
#define OFF_XW   (OFF_WFCH+ (size_t)ND*ND*2)          // xyz+sq float4    256 KB
#define OFF_XW2  (OFF_XW  + (size_t)BN*16)            // pair-packed xyzw 256 KB
#define OFF_IDX  (OFF_XW2 + (size_t)BN*16)            // knn idx          1 MB
#define OFF_WQC  (OFF_IDX + (size_t)BN*NKNN*4)        // col-sum W_q      2 KB
#define OFF_WKC  (OFF_WQC + 2048)                     // col-sum W_k      2 KB
#define OFF_QKB  (OFF_WKC + 2048)                     // bias sums        256 B
#define OFF_QS   (OFF_QKB + 256)                      // qsum             64 KB
#define OFF_KS   (OFF_QS  + (size_t)BN*4)             // ksum             64 KB

// ---------------- W_qkv column sums (for qsum/ksum trick) ----------------
__global__ __launch_bounds__(256) void kcolsum(const float* __restrict__ W,
                                               float* __restrict__ wq,
                                               float* __restrict__ wk) {
  int h = blockIdx.x >> 3, g = blockIdx.x & 7;      // h: 0=q rows,1=k rows
  int t = threadIdx.x, dl = t & 63, s = t >> 6;     // s: e-strip
  const float* Wb = W + (size_t)h * 512 * 512;
  int d = g * 64 + dl;
  float acc = 0.f;
  for (int e = s * 128; e < s * 128 + 128; ++e) acc += Wb[(size_t)e * 512 + d];
  __shared__ float red[4][64];
  red[s][dl] = acc;
  __syncthreads();
  if (s == 0) (h ? wk : wq)[d] = red[0][dl] + red[1][dl] + red[2][dl] + red[3][dl];
}

__global__ __launch_bounds__(512) void kbias(const float* __restrict__ b,
                                             float* __restrict__ qkb) {
  __shared__ float r0[512], r1[512];
  int t = threadIdx.x;
  r0[t] = b[t]; r1[t] = b[512 + t];
  __syncthreads();
  for (int s = 256; s; s >>= 1) {
    if (t < s) { r0[t] += r0[t + s]; r1[t] += r1[t + s]; }
    __syncthreads();
  }
  if (t == 0) { qkb[0] = r0[0]; qkb[1] = r1[0]; }
}

// ---------------- weight conversion to fp16 ----------------
__global__ __launch_bounds__(256) void kconvw(const float* __restrict__ wqkv,
                                              const float* __restrict__ wfc,
                                              half_t* __restrict__ wvh,
                                              half_t* __restrict__ wfch) {
  int i = blockIdx.x * 256 + threadIdx.x;           // 65536 float4 units
  float4 a = ((const float4*)(wqkv + 1024 * 512))[i];
  half4v ha; ha[0]=(half_t)a.x; ha[1]=(half_t)a.y; ha[2]=(half_t)a.z; ha[3]=(half_t)a.w;
  *(half4v*)(wvh + (size_t)i * 4) = ha;
  float4 c = ((const float4*)wfc)[i];
  half4v hc; hc[0]=(half_t)c.x; hc[1]=(half_t)c.y; hc[2]=(half_t)c.z; hc[3]=(half_t)c.w;
  *(half4v*)(wfch + (size_t)i * 4) = hc;
}

// ---------------- x -> fp16 + qsum/ksum (fused) ----------------
__global__ __launch_bounds__(256) void kxh(const float* __restrict__ x,
                                           const float* __restrict__ wq,
                                           const float* __restrict__ wk,
                                           const float* __restrict__ qkb,
                                           half_t* __restrict__ xh,
                                           float* __restrict__ qs,
                                           float* __restrict__ ks) {
  int wid = blockIdx.x * 4 + (threadIdx.x >> 6);    // row
  int l = threadIdx.x & 63;
  size_t base = (size_t)wid * ND + l * 8;
  float4 a0 = *(const float4*)(x + base);
  float4 a1 = *(const float4*)(x + base + 4);
  half8 h;
  h[0]=(half_t)a0.x; h[1]=(half_t)a0.y; h[2]=(half_t)a0.z; h[3]=(half_t)a0.w;
  h[4]=(half_t)a1.x; h[5]=(half_t)a1.y; h[6]=(half_t)a1.z; h[7]=(half_t)a1.w;
  *(half8*)(xh + base) = h;
  float4 q0 = ((const float4*)(wq + l * 8))[0], q1 = ((const float4*)(wq + l * 8))[1];
  float4 k0 = ((const float4*)(wk + l * 8))[0], k1 = ((const float4*)(wk + l * 8))[1];
  float dq = a0.x*q0.x + a0.y*q0.y + a0.z*q0.z + a0.w*q0.w
           + a1.x*q1.x + a1.y*q1.y + a1.z*q1.z + a1.w*q1.w;
  float dk = a0.x*k0.x + a0.y*k0.y + a0.z*k0.z + a0.w*k0.w
           + a1.x*k1.x + a1.y*k1.y + a1.z*k1.z + a1.w*k1.w;
  #pragma unroll
  for (int o = 32; o; o >>= 1) { dq += __shfl_xor(dq, o); dk += __shfl_xor(dk, o); }
  if (l == 0) { qs[wid] = dq + qkb[0]; ks[wid] = dk + qkb[1]; }
}

// ---------------- xyz -> AoS float4 (queries) + pair-packed layout (candidates) ----------------
// xw[i]  = (x,y,z,sq)        sq = plain (x*x+y*y)+z*z, bit-identical to r1-r6
// xw2[b*NN + p]        = (x0,x1,y0,y1) of pair p     (p = 0..NN/2-1)
// xw2[b*NN + NN/2 + p] = (z0,z1,sq0,sq1)
__global__ __launch_bounds__(256) void kxyzw(const float* __restrict__ xyz,
                                             float4* __restrict__ xw,
                                             float4* __restrict__ xw2) {
  int p = blockIdx.x * 256 + threadIdx.x;           // pair id 0..8191
  int b = p >> 12;
  int pl = p & 4095;
  int i0 = b * NN + pl * 2;
  const float* s = xyz + (size_t)i0 * 3;
  float x0 = s[0], y0 = s[1], z0 = s[2];
  float x1 = s[3], y1 = s[4], z1 = s[5];
  float sq0 = __fadd_rn(__fadd_rn(__fmul_rn(x0, x0), __fmul_rn(y0, y0)), __fmul_rn(z0, z0));
  float sq1 = __fadd_rn(__fadd_rn(__fmul_rn(x1, x1), __fmul_rn(y1, y1)), __fmul_rn(z1, z1));
  xw[i0]     = make_float4(x0, y0, z0, sq0);
  xw[i0 + 1] = make_float4(x1, y1, z1, sq1);
  xw2[(size_t)b * NN + pl]          = make_float4(x0, x1, y0, y1);
  xw2[(size_t)b * NN + NN/2 + pl]   = make_float4(z0, z1, sq0, sq1);
}

// ---------------- KNN, two-pass, packed math, double-buffered global_load_lds staging -------
// L2-traffic analysis (r6 post-mortem): direct streaming = 2.1 GB of L2 reads (~61 us);
// block-level LDS staging cuts it 8x (262 MB). Tile = 512 pairs (16 KB), 2 buffers (32 KB),
// async global_load_lds issue overlaps with current-tile compute; __syncthreads()'s implicit
// vmcnt(0) drains the prefetch. 4 blocks/CU retained.
// d2 per component: fma(-2,dot,(qw+cw)) == fsub(fadd(qw,cw), fmul(2,dot)) since 2*dot exact;
// dot = fma(qz,cz, fma(qy,cy, qx*cx)) -- bit-identical to validated r1-r6 stream.
__device__ __forceinline__ void gload16(const void* g, void* l) {
  __builtin_amdgcn_global_load_lds((const __attribute__((address_space(1))) void*)g,
                                   (__attribute__((address_space(3))) void*)l, 16, 0, 0);
}

#define QPW 4
#define KTILE 512
__global__ __launch_bounds__(256, 4) void kknn(const float4* __restrict__ xw,
                                               const float4* __restrict__ xw2,
                                               int* __restrict__ idxo) {
  __shared__ __align__(16) float4 ldsA[2][KTILE];
  __shared__ __align__(16) float4 ldsB[2][KTILE];
  const int tid = threadIdx.x;
  const int l = tid & 63;
  const int w = tid >> 6;
  const int b = blockIdx.x >> 9;
  const int qbase = (blockIdx.x & 511) * (4 * QPW) + w * QPW;
  const float4* xb  = xw  + (size_t)b * NN;
  const float4* xa2 = xw2 + (size_t)b * NN;         // A pairs (x0,x1,y0,y1)
  const float4* xb2 = xa2 + NN / 2;                 // B pairs (z0,z1,sq0,sq1)

  // stage tile t into buffer bi: 512 A-units + 512 B-units, 16B each.
  // global src is per-lane; LDS dest is wave-uniform base (+ lane*16 implicit in HW).
  auto stage = [&](int t, int bi) {
    int ts = t * KTILE;
    gload16(xa2 + ts + w * 64 + l,        (void*)&ldsA[bi][w * 64]);
    gload16(xa2 + ts + 256 + w * 64 + l,  (void*)&ldsA[bi][256 + w * 64]);
    gload16(xb2 + ts + w * 64 + l,        (void*)&ldsB[bi][w * 64]);
    gload16(xb2 + ts + 256 + w * 64 + l,  (void*)&ldsB[bi][256 + w * 64]);
  };

  // loop-invariant packed (splatted) query operands
  f32x2 qxx[QPW], qyy[QPW], qzz[QPW], qww[QPW];
  #pragma unroll
  for (int qi = 0; qi < QPW; ++qi) {
    float4 qp = xb[qbase + qi];
    qxx[qi] = (f32x2){qp.x, qp.x};
    qyy[qi] = (f32x2){qp.y, qp.y};
    qzz[qi] = (f32x2){qp.z, qp.z};
    qww[qi] = (f32x2){qp.w, qp.w};
  }
  const f32x2 m2 = (f32x2){-2.0f, -2.0f};

  // ---- pass 1: independent even/odd per-lane mins ----
  float mind0[QPW], mind1[QPW]; int mini0[QPW], mini1[QPW];
  #pragma unroll
  for (int qi = 0; qi < QPW; ++qi) {
    mind0[qi] = __builtin_inff(); mini0[qi] = 0x7fffffff;
    mind1[qi] = __builtin_inff(); mini1[qi] = 0x7fffffff;
  }

  auto body1 = [&](const float4& A, const float4& Bv, int pg) {
    f32x2 cx = (f32x2){A.x, A.y};
    f32x2 cy = (f32x2){A.z, A.w};
    f32x2 cz = (f32x2){Bv.x, Bv.y};
    f32x2 cw = (f32x2){Bv.z, Bv.w};
    int ci0 = pg * 2;
    #pragma unroll
    for (int qi = 0; qi < QPW; ++qi) {
      f32x2 dot = __builtin_elementwise_fma(qzz[qi], cz,
                    __builtin_elementwise_fma(qyy[qi], cy, qxx[qi] * cx));
      f32x2 s2 = qww[qi] + cw;
      f32x2 d2 = __builtin_elementwise_fma(m2, dot, s2);
      if (d2.x < mind0[qi]) { mind0[qi] = d2.x; mini0[qi] = ci0; }
      if (d2.y < mind1[qi]) { mind1[qi] = d2.y; mini1[qi] = ci0 + 1; }
    }
  };

  stage(0, 0);
  __syncthreads();
  #pragma unroll 2
  for (int t = 0; t < 8; ++t) {
    if (t < 7) stage(t + 1, (t + 1) & 1);
    #pragma unroll
    for (int it = 0; it < 8; ++it) {
      int p = it * 64 + l;
      float4 A  = ldsA[t & 1][p];
      float4 Bv = ldsB[t & 1][p];
      body1(A, Bv, t * KTILE + p);
    }
    __syncthreads();                                 // drains stage(t+1) vmcnt + sync readers
  }

  // merge even/odd (lexicographic (d2, idx): strict < per stream kept lowest idx)
  float mind[QPW]; int mini[QPW];
  #pragma unroll
  for (int qi = 0; qi < QPW; ++qi) {
    bool take1 = (mind1[qi] < mind0[qi]) ||
                 (mind1[qi] == mind0[qi] && mini1[qi] < mini0[qi]);
    mind[qi] = take1 ? mind1[qi] : mind0[qi];
    mini[qi] = take1 ? mini1[qi] : mini0[qi];
  }

  // ---- merge: bitonic sort 64 lane-mins ascending by (d2, idx) ----
  float kd[QPW]; int ki[QPW]; float wst[QPW];
  #pragma unroll
  for (int qi = 0; qi < QPW; ++qi) {
    float d = mind[qi]; int ii = mini[qi];
    #pragma unroll
    for (int k = 2; k <= 64; k <<= 1) {
      #pragma unroll
      for (int j = k >> 1; j > 0; j >>= 1) {
        float od = __shfl_xor(d, j);
        int   oi = __shfl_xor(ii, j);
        bool up = ((l & k) == 0);
        bool lower_lane = ((l & j) == 0);
        bool oless = (od < d) || (od == d && oi < ii);
        bool take = (up == lower_lane) ? oless : !oless;
        if (take) { d = od; ii = oi; }
      }
    }
    kd[qi] = __shfl(d, l & 15);                    // replicate sorted[0..15] to each 16-group
    ki[qi] = __shfl(ii, l & 15);
    wst[qi] = __shfl(d, 15);
  }

  // ---- pass 2: re-stream with tight threshold; rare serial inserts ----
  auto insert = [&](bool ok, float dv, int iv, int qi) {
    unsigned long long m = __ballot(ok);
    while (m) {
      int a = __builtin_ctzll(m);
      m &= m - 1;
      float dc = __shfl(dv, a);
      int ic = __shfl(iv, a);
      bool lower = (kd[qi] < dc) || (kd[qi] == dc && ki[qi] < ic);
      int r = __popcll(__ballot(lower) & 0xFFFFull);
      if (r < 16) {
        float pd = __shfl_up(kd[qi], 1, 16);
        int pi = __shfl_up(ki[qi], 1, 16);
        int pp = l & 15;
        if (pp == r)      { kd[qi] = dc; ki[qi] = ic; }
        else if (pp > r)  { kd[qi] = pd; ki[qi] = pi; }
        wst[qi] = __shfl(kd[qi], 15, 16);
      }
    }
  };

  auto body2 = [&](const float4& A, const float4& Bv, int pg) {
    f32x2 cx = (f32x2){A.x, A.y};
    f32x2 cy = (f32x2){A.z, A.w};
    f32x2 cz = (f32x2){Bv.x, Bv.y};
    f32x2 cw = (f32x2){Bv.z, Bv.w};
    int ci0 = pg * 2;
    #pragma unroll
    for (int qi = 0; qi < QPW; ++qi) {
      f32x2 dot = __builtin_elementwise_fma(qzz[qi], cz,
                    __builtin_elementwise_fma(qyy[qi], cy, qxx[qi] * cx));
      f32x2 s2 = qww[qi] + cw;
      f32x2 d2 = __builtin_elementwise_fma(m2, dot, s2);
      bool ok0 = (d2.x <= wst[qi]) && (ci0 != mini[qi]);
      bool ok1 = (d2.y <= wst[qi]) && (ci0 + 1 != mini[qi]);
      insert(ok0, d2.x, ci0, qi);
      insert(ok1, d2.y, ci0 + 1, qi);
    }
  };

  __syncthreads();
  stage(0, 0);
  __syncthreads();
  #pragma unroll 2
  for (int t = 0; t < 8; ++t) {
    if (t < 7) stage(t + 1, (t + 1) & 1);
    #pragma unroll
    for (int it = 0; it < 8; ++it) {
      int p = it * 64 + l;
      float4 A  = ldsA[t & 1][p];
      float4 Bv = ldsB[t & 1][p];
      body2(A, Bv, t * KTILE + p);
    }
    __syncthreads();
  }

  if (l < 16) {
    #pragma unroll
    for (int qi = 0; qi < QPW; ++qi)
      idxo[((size_t)b * NN + qbase + qi) * NKNN + l] = ki[qi];
  }
}

// ---------------- fp16 MFMA GEMM: C[M=..,512] = A[M,512] @ Bw[512,512]^T ----------------
// 128x128 tile, BK=64, 4 waves (2x2), 16x16x32 f16 MFMA, global_load_lds width-16 staging.
template <int EPI>   // 0: store half(acc+bias) ; 1: store float(acc+bias+resid)
__global__ __launch_bounds__(256) void kgemm(const half_t* __restrict__ A,
                                             const half_t* __restrict__ Bw,
                                             const float* __restrict__ bias,
                                             const float* __restrict__ resid,
                                             void* __restrict__ Cout) {
  __shared__ __align__(16) half_t As[128 * 64];
  __shared__ __align__(16) half_t Bs[128 * 64];
  const int tid = threadIdx.x;
  const int l = tid & 63;
  const int w = tid >> 6;
  const int wm = w >> 1, wn = w & 1;
  const int mt = blockIdx.x >> 2;
  const int nt = blockIdx.x & 3;
  const int lr = l & 15, lg = l >> 4;

  f32x4 acc[4][4];
  #pragma unroll
  for (int i = 0; i < 4; ++i)
    #pragma unroll
    for (int j = 0; j < 4; ++j) acc[i][j] = (f32x4){0.f, 0.f, 0.f, 0.f};

  for (int kt = 0; kt < 8; ++kt) {
    #pragma unroll
    for (int i = 0; i < 4; ++i) {
      int id = i * 256 + tid;
      int rr = id >> 3, cc = id & 7;
      gload16(A + (size_t)(mt * 128 + rr) * ND + kt * 64 + cc * 8,
              (void*)(As + (size_t)(i * 256 + w * 64) * 8));
      gload16(Bw + (size_t)(nt * 128 + rr) * ND + kt * 64 + cc * 8,
              (void*)(Bs + (size_t)(i * 256 + w * 64) * 8));
    }
    __syncthreads();
    #pragma unroll
    for (int kk = 0; kk < 2; ++kk) {
      half8 af[4], bf[4];
      #pragma unroll
      for (int mi = 0; mi < 4; ++mi)
        af[mi] = *(const half8*)(As + (wm * 64 + mi * 16 + lr) * 64 + kk * 32 + lg * 8);
      #pragma unroll
      for (int ni = 0; ni < 4; ++ni)
        bf[ni] = *(const half8*)(Bs + (wn * 64 + ni * 16 + lr) * 64 + kk * 32 + lg * 8);
      #pragma unroll
      for (int mi = 0; mi < 4; ++mi)
        #pragma unroll
        for (int ni = 0; ni < 4; ++ni)
          acc[mi][ni] = __builtin_amdgcn_mfma_f32_16x16x32_f16(af[mi], bf[ni], acc[mi][ni], 0, 0, 0);
    }
    __syncthreads();
  }

  #pragma unroll
  for (int mi = 0; mi < 4; ++mi) {
    #pragma unroll
    for (int ni = 0; ni < 4; ++ni) {
      int col = nt * 128 + wn * 64 + ni * 16 + lr;
      #pragma unroll
      for (int r4 = 0; r4 < 4; ++r4) {
        size_t row = (size_t)mt * 128 + wm * 64 + mi * 16 + lg * 4 + r4;
        float v = acc[mi][ni][r4] + bias[col];
        if (EPI == 0) ((half_t*)Cout)[row * ND + col] = (half_t)v;
        else          ((float*)Cout)[row * ND + col] = v + resid[row * ND + col];
      }
    }
  }
}

// ---------------- attention: logits -> softmax -> weighted v gather ----------------
__global__ __launch_bounds__(256) void kattn(const int* __restrict__ idx,
                                             const float* __restrict__ qs,
                                             const float* __restrict__ ks,
                                             const half_t* __restrict__ vh,
                                             half_t* __restrict__ xoh) {
  int wid = blockIdx.x * 4 + (threadIdx.x >> 6);
  int l = threadIdx.x & 63;
  int b = wid >> 13;
  int j = l & 15;
  int nb = idx[(size_t)wid * NKNN + j];
  float ksv = ks[(size_t)b * NN + nb];
  float logit = __fdiv_rn(__fmul_rn(qs[wid], ksv), 22.627416997969522f); // /sqrt(512)
  float mx = logit;
  #pragma unroll
  for (int o = 8; o; o >>= 1) mx = fmaxf(mx, __shfl_xor(mx, o, 16));
  float e = expf(logit - mx);
  float s = e;
  #pragma unroll
  for (int o = 8; o; o >>= 1) s += __shfl_xor(s, o, 16);
  float p = e / s;

  float acc[8] = {0.f, 0.f, 0.f, 0.f, 0.f, 0.f, 0.f, 0.f};
  #pragma unroll
  for (int t16 = 0; t16 < 16; ++t16) {
    float wj = __shfl(p, t16, 16);
    int ij = __shfl(nb, t16, 16);
    const half8 vv = *(const half8*)(vh + ((size_t)b * NN + ij) * ND + l * 8);
    #pragma unroll
    for (int u = 0; u < 8; ++u) acc[u] += wj * (float)vv[u];
  }
  half8 ho;
  #pragma unroll
  for (int u = 0; u < 8; ++u) ho[u] = (half_t)acc[u];
  *(half8*)(xoh + (size_t)wid * ND + l * 8) = ho;
}

// ---------------- launcher ----------------
extern "C" void kernel_launch(void* const* d_in, const int* in_sizes, int n_in,
                              void* d_out, int out_size, void* d_ws, size_t ws_size,
                              hipStream_t stream) {
  const float* x    = (const float*)d_in[0];
  const float* xyz  = (const float*)d_in[1];
  const float* wqkv = (const float*)d_in[2];
  const float* bqkv = (const float*)d_in[3];
  const float* wfc  = (const float*)d_in[4];
  const float* bfc  = (const float*)d_in[5];
  char* ws = (char*)d_ws;
  half_t* xh   = (half_t*)(ws + OFF_XH);
  half_t* vh   = (half_t*)(ws + OFF_VH);
  half_t* xoh  = (half_t*)(ws + OFF_XOH);
  half_t* wvh  = (half_t*)(ws + OFF_WVH);
  half_t* wfch = (half_t*)(ws + OFF_WFCH);
  float4* xw   = (float4*)(ws + OFF_XW);
  float4* xw2  = (float4*)(ws + OFF_XW2);
  int*    idx  = (int*)(ws + OFF_IDX);
  float*  wqc  = (float*)(ws + OFF_WQC);
  float*  wkc  = (float*)(ws + OFF_WKC);
  float*  qkb  = (float*)(ws + OFF_QKB);
  float*  qs   = (float*)(ws + OFF_QS);
  float*  ks   = (float*)(ws + OFF_KS);

  kcolsum<<<dim3(16),  dim3(256), 0, stream>>>(wqkv, wqc, wkc);
  kbias  <<<dim3(1),   dim3(512), 0, stream>>>(bqkv, qkb);
  kconvw <<<dim3(256), dim3(256), 0, stream>>>(wqkv, wfc, wvh, wfch);
  kxyzw  <<<dim3(32),  dim3(256), 0, stream>>>(xyz, xw, xw2);
  kxh    <<<dim3(4096),dim3(256), 0, stream>>>(x, wqc, wkc, qkb, xh, qs, ks);
  kknn   <<<dim3(1024),dim3(256), 0, stream>>>(xw, xw2, idx);
  kgemm<0><<<dim3(512),dim3(256), 0, stream>>>(xh, wvh, bqkv + 1024, (const float*)nullptr, (void*)vh);
  kattn  <<<dim3(4096),dim3(256), 0, stream>>>(idx, qs, ks, vh, xoh);
  kgemm<1><<<dim3(512),dim3(256), 0, stream>>>(xoh, wfch, bfc, x, d_out);
}

// Round 8
// 172.302 us; speedup vs baseline: 1.0077x; 1.0077x over previous
//
#include <hip/hip_runtime.h>

typedef _Float16 half_t;
typedef _Float16 half8 __attribute__((ext_vector_type(8)));
typedef _Float16 half4v __attribute__((ext_vector_type(4)));
typedef float f32x4 __attribute__((ext_vector_type(4)));
typedef float f32x2 __attribute__((ext_vector_type(2)));

#define NB 2
#define NN 8192
#define ND 512
#define NKNN 16
#define BN (NB*NN)

// ---------------- workspace layout (bytes, all 256-aligned) ----------------
#define OFF_XH   0ull                                 // (unused since r8)
#define OFF_VH   (OFF_XH  + (size_t)BN*ND*2)          // v in fp16        16.8 MB
#define OFF_XOH  (OFF_VH  + (size_t)BN*ND*2)          // x_out in fp16    16.8 MB
#define OFF_WVH  (OFF_XOH + (size_t)BN*ND*2)          // W_v fp16         512 KB
#define OFF_WFCH (OFF_WVH + (size_t)ND*ND*2)          // W_fc fp16        512 KB
#define OFF_XW   (OFF_WFCH+ (size_t)ND*ND*2)          // xyz+sq float4    256 KB
#define OFF_XW2  (OFF_XW  + (size_t)BN*16)            // pair-packed xyzw 256 KB
#define OFF_IDX  (OFF_XW2 + (size_t)BN*16)            // knn idx          1 MB
#define OFF_WQC  (OFF_IDX + (size_t)BN*NKNN*4)        // col-sum W_q      2 KB
#define OFF_WKC  (OFF_WQC + 2048)                     // col-sum W_k      2 KB
#define OFF_QKB  (OFF_WKC + 2048)                     // bias sums        256 B
#define OFF_QS   (OFF_QKB + 256)                      // qsum             64 KB
#define OFF_KS   (OFF_QS  + (size_t)BN*4)             // ksum             64 KB

__device__ __forceinline__ void gload16(const void* g, void* l) {
  __builtin_amdgcn_global_load_lds((const __attribute__((address_space(1))) void*)g,
                                   (__attribute__((address_space(3))) void*)l, 16, 0, 0);
}

// ---------------- fused setup: colsum(16) | bias(1) | convw(256) | xyzw(32) ----------------
__global__ __launch_bounds__(256) void ksetup(const float* __restrict__ wqkv,
                                              const float* __restrict__ bqkv,
                                              const float* __restrict__ wfc,
                                              const float* __restrict__ xyz,
                                              float* __restrict__ wq, float* __restrict__ wk,
                                              float* __restrict__ qkb,
                                              half_t* __restrict__ wvh, half_t* __restrict__ wfch,
                                              float4* __restrict__ xw, float4* __restrict__ xw2) {
  const int blk = blockIdx.x;
  const int t = threadIdx.x;
  if (blk < 16) {                                    // W_qkv column sums (q,k halves)
    int h = blk >> 3, g = blk & 7;
    int dl = t & 63, s = t >> 6;
    const float* Wb = wqkv + (size_t)h * 512 * 512;
    int d = g * 64 + dl;
    float acc = 0.f;
    for (int e = s * 128; e < s * 128 + 128; ++e) acc += Wb[(size_t)e * 512 + d];
    __shared__ float red[4][64];
    red[s][dl] = acc;
    __syncthreads();
    if (s == 0) (h ? wk : wq)[d] = red[0][dl] + red[1][dl] + red[2][dl] + red[3][dl];
  } else if (blk == 16) {                            // bias sums (b_qkv is zeros; order-free)
    __shared__ float r0[256], r1[256];
    r0[t] = bqkv[t] + bqkv[t + 256];
    r1[t] = bqkv[512 + t] + bqkv[768 + t];
    __syncthreads();
    for (int s = 128; s; s >>= 1) {
      if (t < s) { r0[t] += r0[t + s]; r1[t] += r1[t + s]; }
      __syncthreads();
    }
    if (t == 0) { qkb[0] = r0[0]; qkb[1] = r1[0]; }
  } else if (blk < 273) {                            // weight fp16 conversion
    int i = (blk - 17) * 256 + t;
    float4 a = ((const float4*)(wqkv + 1024 * 512))[i];
    half4v ha; ha[0]=(half_t)a.x; ha[1]=(half_t)a.y; ha[2]=(half_t)a.z; ha[3]=(half_t)a.w;
    *(half4v*)(wvh + (size_t)i * 4) = ha;
    float4 c = ((const float4*)wfc)[i];
    half4v hc; hc[0]=(half_t)c.x; hc[1]=(half_t)c.y; hc[2]=(half_t)c.z; hc[3]=(half_t)c.w;
    *(half4v*)(wfch + (size_t)i * 4) = hc;
  } else {                                           // xyz -> xw (AoS) + xw2 (pair-packed)
    int p = (blk - 273) * 256 + t;
    int b = p >> 12;
    int pl = p & 4095;
    int i0 = b * NN + pl * 2;
    const float* s = xyz + (size_t)i0 * 3;
    float x0 = s[0], y0 = s[1], z0 = s[2];
    float x1 = s[3], y1 = s[4], z1 = s[5];
    float sq0 = __fadd_rn(__fadd_rn(__fmul_rn(x0, x0), __fmul_rn(y0, y0)), __fmul_rn(z0, z0));
    float sq1 = __fadd_rn(__fadd_rn(__fmul_rn(x1, x1), __fmul_rn(y1, y1)), __fmul_rn(z1, z1));
    xw[i0]     = make_float4(x0, y0, z0, sq0);
    xw[i0 + 1] = make_float4(x1, y1, z1, sq1);
    xw2[(size_t)b * NN + pl]        = make_float4(x0, x1, y0, y1);
    xw2[(size_t)b * NN + NN/2 + pl] = make_float4(z0, z1, sq0, sq1);
  }
}

// ---------------- fused big launch: knn(1024) | xh-sums(1024) | gemm0(512), interleaved %5 ----
// knn body = r6 verbatim (best variant, 83 us): two-pass, packed math, prefetch-pipelined
// direct L2 streaming. gemm0 reads x as f32 and converts during staging (bit-identical to
// the old kxh (half)x conversion) -> no xh buffer, no dependency. xh-sums computes qsum/ksum
// only. The three classes are mutually independent; interleaving hides gemm's MFMA work and
// xh's memory work under knn's VALU-bound 83 us.
#define QPW 4
__global__ __launch_bounds__(256, 4) void kbig(const float4* __restrict__ xw,
                                               const float4* __restrict__ xw2,
                                               int* __restrict__ idxo,
                                               const float* __restrict__ x,
                                               const float* __restrict__ wq,
                                               const float* __restrict__ wk,
                                               const float* __restrict__ qkb,
                                               float* __restrict__ qs,
                                               float* __restrict__ ks,
                                               const half_t* __restrict__ wvh,
                                               const float* __restrict__ bv,
                                               half_t* __restrict__ vh) {
  const int g5 = blockIdx.x / 5;
  const int r5 = blockIdx.x % 5;
  const int tid = threadIdx.x;
  const int l = tid & 63;
  const int w = tid >> 6;

  if (r5 < 2) {
    // ================= KNN (r6 verbatim) =================
    const int bid = g5 * 2 + r5;                    // 0..1023
    const int b = bid >> 9;
    const int qbase = (bid & 511) * (4 * QPW) + w * QPW;
    const float4* xb  = xw  + (size_t)b * NN;
    const float4* xa2 = xw2 + (size_t)b * NN;
    const float4* xb2 = xa2 + NN / 2;

    f32x2 qxx[QPW], qyy[QPW], qzz[QPW], qww[QPW];
    #pragma unroll
    for (int qi = 0; qi < QPW; ++qi) {
      float4 qp = xb[qbase + qi];
      qxx[qi] = (f32x2){qp.x, qp.x};
      qyy[qi] = (f32x2){qp.y, qp.y};
      qzz[qi] = (f32x2){qp.z, qp.z};
      qww[qi] = (f32x2){qp.w, qp.w};
    }
    const f32x2 m2 = (f32x2){-2.0f, -2.0f};

    float mind0[QPW], mind1[QPW]; int mini0[QPW], mini1[QPW];
    #pragma unroll
    for (int qi = 0; qi < QPW; ++qi) {
      mind0[qi] = __builtin_inff(); mini0[qi] = 0x7fffffff;
      mind1[qi] = __builtin_inff(); mini1[qi] = 0x7fffffff;
    }

    auto body1 = [&](const float4& A, const float4& Bv, int it) {
      f32x2 cx = (f32x2){A.x, A.y};
      f32x2 cy = (f32x2){A.z, A.w};
      f32x2 cz = (f32x2){Bv.x, Bv.y};
      f32x2 cw = (f32x2){Bv.z, Bv.w};
      int ci0 = (it * 64 + l) * 2;
      #pragma unroll
      for (int qi = 0; qi < QPW; ++qi) {
        f32x2 dot = __builtin_elementwise_fma(qzz[qi], cz,
                      __builtin_elementwise_fma(qyy[qi], cy, qxx[qi] * cx));
        f32x2 s2 = qww[qi] + cw;
        f32x2 d2 = __builtin_elementwise_fma(m2, dot, s2);
        if (d2.x < mind0[qi]) { mind0[qi] = d2.x; mini0[qi] = ci0; }
        if (d2.y < mind1[qi]) { mind1[qi] = d2.y; mini1[qi] = ci0 + 1; }
      }
    };

    {
      float4 A0 = xa2[l],      B0 = xb2[l];
      float4 A1 = xa2[64 + l], B1 = xb2[64 + l];
      for (int tt = 0; tt < 4; ++tt) {
        __syncthreads();
        #pragma unroll
        for (int its = 0; its < 16; its += 2) {
          int it = tt * 16 + its;
          int pf = it + 2; if (pf > 62) pf = 62;
          float4 A2 = xa2[pf * 64 + l];
          float4 B2 = xb2[pf * 64 + l];
          float4 A3 = xa2[pf * 64 + 64 + l];
          float4 B3 = xb2[pf * 64 + 64 + l];
          body1(A0, B0, it);
          body1(A1, B1, it + 1);
          A0 = A2; B0 = B2; A1 = A3; B1 = B3;
        }
      }
    }

    float mind[QPW]; int mini[QPW];
    #pragma unroll
    for (int qi = 0; qi < QPW; ++qi) {
      bool take1 = (mind1[qi] < mind0[qi]) ||
                   (mind1[qi] == mind0[qi] && mini1[qi] < mini0[qi]);
      mind[qi] = take1 ? mind1[qi] : mind0[qi];
      mini[qi] = take1 ? mini1[qi] : mini0[qi];
    }

    float kd[QPW]; int ki[QPW]; float wst[QPW];
    #pragma unroll
    for (int qi = 0; qi < QPW; ++qi) {
      float d = mind[qi]; int ii = mini[qi];
      #pragma unroll
      for (int k = 2; k <= 64; k <<= 1) {
        #pragma unroll
        for (int j = k >> 1; j > 0; j >>= 1) {
          float od = __shfl_xor(d, j);
          int   oi = __shfl_xor(ii, j);
          bool up = ((l & k) == 0);
          bool lower_lane = ((l & j) == 0);
          bool oless = (od < d) || (od == d && oi < ii);
          bool take = (up == lower_lane) ? oless : !oless;
          if (take) { d = od; ii = oi; }
        }
      }
      kd[qi] = __shfl(d, l & 15);
      ki[qi] = __shfl(ii, l & 15);
      wst[qi] = __shfl(d, 15);
    }

    auto insert = [&](bool ok, float dv, int iv, int qi) {
      unsigned long long m = __ballot(ok);
      while (m) {
        int a = __builtin_ctzll(m);
        m &= m - 1;
        float dc = __shfl(dv, a);
        int ic = __shfl(iv, a);
        bool lower = (kd[qi] < dc) || (kd[qi] == dc && ki[qi] < ic);
        int r = __popcll(__ballot(lower) & 0xFFFFull);
        if (r < 16) {
          float pd = __shfl_up(kd[qi], 1, 16);
          int pi = __shfl_up(ki[qi], 1, 16);
          int pp = l & 15;
          if (pp == r)      { kd[qi] = dc; ki[qi] = ic; }
          else if (pp > r)  { kd[qi] = pd; ki[qi] = pi; }
          wst[qi] = __shfl(kd[qi], 15, 16);
        }
      }
    };

    auto body2 = [&](const float4& A, const float4& Bv, int it) {
      f32x2 cx = (f32x2){A.x, A.y};
      f32x2 cy = (f32x2){A.z, A.w};
      f32x2 cz = (f32x2){Bv.x, Bv.y};
      f32x2 cw = (f32x2){Bv.z, Bv.w};
      int ci0 = (it * 64 + l) * 2;
      #pragma unroll
      for (int qi = 0; qi < QPW; ++qi) {
        f32x2 dot = __builtin_elementwise_fma(qzz[qi], cz,
                      __builtin_elementwise_fma(qyy[qi], cy, qxx[qi] * cx));
        f32x2 s2 = qww[qi] + cw;
        f32x2 d2 = __builtin_elementwise_fma(m2, dot, s2);
        bool ok0 = (d2.x <= wst[qi]) && (ci0 != mini[qi]);
        bool ok1 = (d2.y <= wst[qi]) && (ci0 + 1 != mini[qi]);
        insert(ok0, d2.x, ci0, qi);
        insert(ok1, d2.y, ci0 + 1, qi);
      }
    };

    {
      float4 A0 = xa2[l],      B0 = xb2[l];
      float4 A1 = xa2[64 + l], B1 = xb2[64 + l];
      for (int tt = 0; tt < 4; ++tt) {
        __syncthreads();
        #pragma unroll
        for (int its = 0; its < 16; its += 2) {
          int it = tt * 16 + its;
          int pf = it + 2; if (pf > 62) pf = 62;
          float4 A2 = xa2[pf * 64 + l];
          float4 B2 = xb2[pf * 64 + l];
          float4 A3 = xa2[pf * 64 + 64 + l];
          float4 B3 = xb2[pf * 64 + 64 + l];
          body2(A0, B0, it);
          body2(A1, B1, it + 1);
          A0 = A2; B0 = B2; A1 = A3; B1 = B3;
        }
      }
    }

    if (l < 16) {
      #pragma unroll
      for (int qi = 0; qi < QPW; ++qi)
        idxo[((size_t)b * NN + qbase + qi) * NKNN + l] = ki[qi];
    }
  } else if (r5 < 4) {
    // ================= qsum/ksum (4 rows per wave) =================
    const int bid = g5 * 2 + (r5 - 2);              // 0..1023
    float4 q0 = ((const float4*)(wq + l * 8))[0], q1 = ((const float4*)(wq + l * 8))[1];
    float4 k0 = ((const float4*)(wk + l * 8))[0], k1 = ((const float4*)(wk + l * 8))[1];
    float qb0 = qkb[0], qb1 = qkb[1];
    #pragma unroll
    for (int rr = 0; rr < 4; ++rr) {
      int wid = bid * 16 + w * 4 + rr;
      size_t base = (size_t)wid * ND + l * 8;
      float4 a0 = *(const float4*)(x + base);
      float4 a1 = *(const float4*)(x + base + 4);
      float dq = a0.x*q0.x + a0.y*q0.y + a0.z*q0.z + a0.w*q0.w
               + a1.x*q1.x + a1.y*q1.y + a1.z*q1.z + a1.w*q1.w;
      float dk = a0.x*k0.x + a0.y*k0.y + a0.z*k0.z + a0.w*k0.w
               + a1.x*k1.x + a1.y*k1.y + a1.z*k1.z + a1.w*k1.w;
      #pragma unroll
      for (int o = 32; o; o >>= 1) { dq += __shfl_xor(dq, o); dk += __shfl_xor(dk, o); }
      if (l == 0) { qs[wid] = dq + qb0; ks[wid] = dk + qb1; }
    }
  } else {
    // ================= gemm0: vh = half(x_f32 @ Wv^T + bv) =================
    __shared__ __align__(16) half_t As[128 * 64];
    __shared__ __align__(16) half_t Bs[128 * 64];
    const int gbid = g5;                            // 0..511
    const int wm = w >> 1, wn = w & 1;
    const int mt = gbid >> 2;
    const int nt = gbid & 3;
    const int lr = l & 15, lg = l >> 4;

    f32x4 acc[4][4];
    #pragma unroll
    for (int i = 0; i < 4; ++i)
      #pragma unroll
      for (int j = 0; j < 4; ++j) acc[i][j] = (f32x4){0.f, 0.f, 0.f, 0.f};

    for (int kt = 0; kt < 8; ++kt) {
      #pragma unroll
      for (int i = 0; i < 4; ++i) {
        int id = i * 256 + tid;
        int rr = id >> 3, cc = id & 7;
        const float* src = x + (size_t)(mt * 128 + rr) * ND + kt * 64 + cc * 8;
        float4 f0 = *(const float4*)src;
        float4 f1 = *(const float4*)(src + 4);
        half8 h;
        h[0]=(half_t)f0.x; h[1]=(half_t)f0.y; h[2]=(half_t)f0.z; h[3]=(half_t)f0.w;
        h[4]=(half_t)f1.x; h[5]=(half_t)f1.y; h[6]=(half_t)f1.z; h[7]=(half_t)f1.w;
        *(half8*)(As + (size_t)id * 8) = h;
        gload16(wvh + (size_t)(nt * 128 + rr) * ND + kt * 64 + cc * 8,
                (void*)(Bs + (size_t)(i * 256 + w * 64) * 8));
      }
      __syncthreads();
      #pragma unroll
      for (int kk = 0; kk < 2; ++kk) {
        half8 af[4], bf[4];
        #pragma unroll
        for (int mi = 0; mi < 4; ++mi)
          af[mi] = *(const half8*)(As + (wm * 64 + mi * 16 + lr) * 64 + kk * 32 + lg * 8);
        #pragma unroll
        for (int ni = 0; ni < 4; ++ni)
          bf[ni] = *(const half8*)(Bs + (wn * 64 + ni * 16 + lr) * 64 + kk * 32 + lg * 8);
        #pragma unroll
        for (int mi = 0; mi < 4; ++mi)
          #pragma unroll
          for (int ni = 0; ni < 4; ++ni)
            acc[mi][ni] = __builtin_amdgcn_mfma_f32_16x16x32_f16(af[mi], bf[ni], acc[mi][ni], 0, 0, 0);
      }
      __syncthreads();
    }

    #pragma unroll
    for (int mi = 0; mi < 4; ++mi) {
      #pragma unroll
      for (int ni = 0; ni < 4; ++ni) {
        int col = nt * 128 + wn * 64 + ni * 16 + lr;
        #pragma unroll
        for (int r4 = 0; r4 < 4; ++r4) {
          size_t row = (size_t)mt * 128 + wm * 64 + mi * 16 + lg * 4 + r4;
          vh[row * ND + col] = (half_t)(acc[mi][ni][r4] + bv[col]);
        }
      }
    }
  }
}

// ---------------- attention: logits -> softmax -> weighted v gather ----------------
__global__ __launch_bounds__(256) void kattn(const int* __restrict__ idx,
                                             const float* __restrict__ qs,
                                             const float* __restrict__ ks,
                                             const half_t* __restrict__ vh,
                                             half_t* __restrict__ xoh) {
  int wid = blockIdx.x * 4 + (threadIdx.x >> 6);
  int l = threadIdx.x & 63;
  int b = wid >> 13;
  int j = l & 15;
  int nb = idx[(size_t)wid * NKNN + j];
  float ksv = ks[(size_t)b * NN + nb];
  float logit = __fdiv_rn(__fmul_rn(qs[wid], ksv), 22.627416997969522f); // /sqrt(512)
  float mx = logit;
  #pragma unroll
  for (int o = 8; o; o >>= 1) mx = fmaxf(mx, __shfl_xor(mx, o, 16));
  float e = expf(logit - mx);
  float s = e;
  #pragma unroll
  for (int o = 8; o; o >>= 1) s += __shfl_xor(s, o, 16);
  float p = e / s;

  float acc[8] = {0.f, 0.f, 0.f, 0.f, 0.f, 0.f, 0.f, 0.f};
  #pragma unroll
  for (int t16 = 0; t16 < 16; ++t16) {
    float wj = __shfl(p, t16, 16);
    int ij = __shfl(nb, t16, 16);
    const half8 vv = *(const half8*)(vh + ((size_t)b * NN + ij) * ND + l * 8);
    #pragma unroll
    for (int u = 0; u < 8; ++u) acc[u] += wj * (float)vv[u];
  }
  half8 ho;
  #pragma unroll
  for (int u = 0; u < 8; ++u) ho[u] = (half_t)acc[u];
  *(half8*)(xoh + (size_t)wid * ND + l * 8) = ho;
}

// ---------------- gemm1: out = float(xoh_f16 @ Wfc^T + bfc + x) ----------------
__global__ __launch_bounds__(256) void kgemm1(const half_t* __restrict__ A,
                                              const half_t* __restrict__ Bw,
                                              const float* __restrict__ bias,
                                              const float* __restrict__ resid,
                                              float* __restrict__ Cout) {
  __shared__ __align__(16) half_t As[128 * 64];
  __shared__ __align__(16) half_t Bs[128 * 64];
  const int tid = threadIdx.x;
  const int l = tid & 63;
  const int w = tid >> 6;
  const int wm = w >> 1, wn = w & 1;
  const int mt = blockIdx.x >> 2;
  const int nt = blockIdx.x & 3;
  const int lr = l & 15, lg = l >> 4;

  f32x4 acc[4][4];
  #pragma unroll
  for (int i = 0; i < 4; ++i)
    #pragma unroll
    for (int j = 0; j < 4; ++j) acc[i][j] = (f32x4){0.f, 0.f, 0.f, 0.f};

  for (int kt = 0; kt < 8; ++kt) {
    #pragma unroll
    for (int i = 0; i < 4; ++i) {
      int id = i * 256 + tid;
      int rr = id >> 3, cc = id & 7;
      gload16(A + (size_t)(mt * 128 + rr) * ND + kt * 64 + cc * 8,
              (void*)(As + (size_t)(i * 256 + w * 64) * 8));
      gload16(Bw + (size_t)(nt * 128 + rr) * ND + kt * 64 + cc * 8,
              (void*)(Bs + (size_t)(i * 256 + w * 64) * 8));
    }
    __syncthreads();
    #pragma unroll
    for (int kk = 0; kk < 2; ++kk) {
      half8 af[4], bf[4];
      #pragma unroll
      for (int mi = 0; mi < 4; ++mi)
        af[mi] = *(const half8*)(As + (wm * 64 + mi * 16 + lr) * 64 + kk * 32 + lg * 8);
      #pragma unroll
      for (int ni = 0; ni < 4; ++ni)
        bf[ni] = *(const half8*)(Bs + (wn * 64 + ni * 16 + lr) * 64 + kk * 32 + lg * 8);
      #pragma unroll
      for (int mi = 0; mi < 4; ++mi)
        #pragma unroll
        for (int ni = 0; ni < 4; ++ni)
          acc[mi][ni] = __builtin_amdgcn_mfma_f32_16x16x32_f16(af[mi], bf[ni], acc[mi][ni], 0, 0, 0);
    }
    __syncthreads();
  }

  #pragma unroll
  for (int mi = 0; mi < 4; ++mi) {
    #pragma unroll
    for (int ni = 0; ni < 4; ++ni) {
      int col = nt * 128 + wn * 64 + ni * 16 + lr;
      #pragma unroll
      for (int r4 = 0; r4 < 4; ++r4) {
        size_t row = (size_t)mt * 128 + wm * 64 + mi * 16 + lg * 4 + r4;
        Cout[row * ND + col] = acc[mi][ni][r4] + bias[col] + resid[row * ND + col];
      }
    }
  }
}

// ---------------- launcher ----------------
extern "C" void kernel_launch(void* const* d_in, const int* in_sizes, int n_in,
                              void* d_out, int out_size, void* d_ws, size_t ws_size,
                              hipStream_t stream) {
  const float* x    = (const float*)d_in[0];
  const float* xyz  = (const float*)d_in[1];
  const float* wqkv = (const float*)d_in[2];
  const float* bqkv = (const float*)d_in[3];
  const float* wfc  = (const float*)d_in[4];
  const float* bfc  = (const float*)d_in[5];
  char* ws = (char*)d_ws;
  half_t* vh   = (half_t*)(ws + OFF_VH);
  half_t* xoh  = (half_t*)(ws + OFF_XOH);
  half_t* wvh  = (half_t*)(ws + OFF_WVH);
  half_t* wfch = (half_t*)(ws + OFF_WFCH);
  float4* xw   = (float4*)(ws + OFF_XW);
  float4* xw2  = (float4*)(ws + OFF_XW2);
  int*    idx  = (int*)(ws + OFF_IDX);
  float*  wqc  = (float*)(ws + OFF_WQC);
  float*  wkc  = (float*)(ws + OFF_WKC);
  float*  qkb  = (float*)(ws + OFF_QKB);
  float*  qs   = (float*)(ws + OFF_QS);
  float*  ks   = (float*)(ws + OFF_KS);

  ksetup<<<dim3(305), dim3(256), 0, stream>>>(wqkv, bqkv, wfc, xyz,
                                              wqc, wkc, qkb, wvh, wfch, xw, xw2);
  kbig  <<<dim3(2560),dim3(256), 0, stream>>>(xw, xw2, idx, x, wqc, wkc, qkb,
                                              qs, ks, wvh, bqkv + 1024, vh);
  kattn <<<dim3(4096),dim3(256), 0, stream>>>(idx, qs, ks, vh, xoh);
  kgemm1<<<dim3(512), dim3(256), 0, stream>>>(xoh, wfch, bfc, x, (float*)d_out);
}

// Round 9
// 156.470 us; speedup vs baseline: 1.1097x; 1.1012x over previous
//
#include <hip/hip_runtime.h>

typedef _Float16 half_t;
typedef _Float16 half8 __attribute__((ext_vector_type(8)));
typedef _Float16 half4v __attribute__((ext_vector_type(4)));
typedef float f32x4 __attribute__((ext_vector_type(4)));
typedef float f32x2 __attribute__((ext_vector_type(2)));

#define NB 2
#define NN 8192
#define ND 512
#define NKNN 16
#define BN (NB*NN)

// ---------------- workspace layout (bytes, all 256-aligned) ----------------
#define OFF_XH   0ull                                 // x in fp16        16.8 MB
#define OFF_VH   (OFF_XH  + (size_t)BN*ND*2)          // v in fp16        16.8 MB
#define OFF_XOH  (OFF_VH  + (size_t)BN*ND*2)          // x_out in fp16    16.8 MB
#define OFF_WVH  (OFF_XOH + (size_t)BN*ND*2)          // W_v fp16         512 KB
#define OFF_WFCH (OFF_WVH + (size_t)ND*ND*2)          // W_fc fp16        512 KB
#define OFF_XW   (OFF_WFCH+ (size_t)ND*ND*2)          // xyz+sq float4    256 KB
#define OFF_XW2  (OFF_XW  + (size_t)BN*16)            // pair-packed xyzw 256 KB
#define OFF_IDX  (OFF_XW2 + (size_t)BN*16)            // knn idx          1 MB
#define OFF_WQC  (OFF_IDX + (size_t)BN*NKNN*4)        // col-sum W_q      2 KB
#define OFF_WKC  (OFF_WQC + 2048)                     // col-sum W_k      2 KB
#define OFF_QKB  (OFF_WKC + 2048)                     // bias sums        256 B
#define OFF_QS   (OFF_QKB + 256)                      // qsum             64 KB
#define OFF_KS   (OFF_QS  + (size_t)BN*4)             // ksum             64 KB

__device__ __forceinline__ void gload16(const void* g, void* l) {
  __builtin_amdgcn_global_load_lds((const __attribute__((address_space(1))) void*)g,
                                   (__attribute__((address_space(3))) void*)l, 16, 0, 0);
}

// ---------------- fused setup: colsum(16) | bias(1) | convw(256) | xyzw(32) ----------------
__global__ __launch_bounds__(256) void ksetup(const float* __restrict__ wqkv,
                                              const float* __restrict__ bqkv,
                                              const float* __restrict__ wfc,
                                              const float* __restrict__ xyz,
                                              float* __restrict__ wq, float* __restrict__ wk,
                                              float* __restrict__ qkb,
                                              half_t* __restrict__ wvh, half_t* __restrict__ wfch,
                                              float4* __restrict__ xw, float4* __restrict__ xw2) {
  const int blk = blockIdx.x;
  const int t = threadIdx.x;
  if (blk < 16) {                                    // W_qkv column sums (q,k halves)
    int h = blk >> 3, g = blk & 7;
    int dl = t & 63, s = t >> 6;
    const float* Wb = wqkv + (size_t)h * 512 * 512;
    int d = g * 64 + dl;
    float acc = 0.f;
    for (int e = s * 128; e < s * 128 + 128; ++e) acc += Wb[(size_t)e * 512 + d];
    __shared__ float red[4][64];
    red[s][dl] = acc;
    __syncthreads();
    if (s == 0) (h ? wk : wq)[d] = red[0][dl] + red[1][dl] + red[2][dl] + red[3][dl];
  } else if (blk == 16) {                            // bias sums (b_qkv is zeros; order-free)
    __shared__ float r0[256], r1[256];
    r0[t] = bqkv[t] + bqkv[t + 256];
    r1[t] = bqkv[512 + t] + bqkv[768 + t];
    __syncthreads();
    for (int s = 128; s; s >>= 1) {
      if (t < s) { r0[t] += r0[t + s]; r1[t] += r1[t + s]; }
      __syncthreads();
    }
    if (t == 0) { qkb[0] = r0[0]; qkb[1] = r1[0]; }
  } else if (blk < 273) {                            // weight fp16 conversion
    int i = (blk - 17) * 256 + t;
    float4 a = ((const float4*)(wqkv + 1024 * 512))[i];
    half4v ha; ha[0]=(half_t)a.x; ha[1]=(half_t)a.y; ha[2]=(half_t)a.z; ha[3]=(half_t)a.w;
    *(half4v*)(wvh + (size_t)i * 4) = ha;
    float4 c = ((const float4*)wfc)[i];
    half4v hc; hc[0]=(half_t)c.x; hc[1]=(half_t)c.y; hc[2]=(half_t)c.z; hc[3]=(half_t)c.w;
    *(half4v*)(wfch + (size_t)i * 4) = hc;
  } else {                                           // xyz -> xw (AoS) + xw2 (pair-packed)
    int p = (blk - 273) * 256 + t;
    int b = p >> 12;
    int pl = p & 4095;
    int i0 = b * NN + pl * 2;
    const float* s = xyz + (size_t)i0 * 3;
    float x0 = s[0], y0 = s[1], z0 = s[2];
    float x1 = s[3], y1 = s[4], z1 = s[5];
    float sq0 = __fadd_rn(__fadd_rn(__fmul_rn(x0, x0), __fmul_rn(y0, y0)), __fmul_rn(z0, z0));
    float sq1 = __fadd_rn(__fadd_rn(__fmul_rn(x1, x1), __fmul_rn(y1, y1)), __fmul_rn(z1, z1));
    xw[i0]     = make_float4(x0, y0, z0, sq0);
    xw[i0 + 1] = make_float4(x1, y1, z1, sq1);
    xw2[(size_t)b * NN + pl]        = make_float4(x0, x1, y0, y1);
    xw2[(size_t)b * NN + NN/2 + pl] = make_float4(z0, z1, sq0, sq1);
  }
}

// ---------------- x -> fp16 + qsum/ksum (fused; r6 proven) ----------------
__global__ __launch_bounds__(256) void kxh(const float* __restrict__ x,
                                           const float* __restrict__ wq,
                                           const float* __restrict__ wk,
                                           const float* __restrict__ qkb,
                                           half_t* __restrict__ xh,
                                           float* __restrict__ qs,
                                           float* __restrict__ ks) {
  int wid = blockIdx.x * 4 + (threadIdx.x >> 6);    // row
  int l = threadIdx.x & 63;
  size_t base = (size_t)wid * ND + l * 8;
  float4 a0 = *(const float4*)(x + base);
  float4 a1 = *(const float4*)(x + base + 4);
  half8 h;
  h[0]=(half_t)a0.x; h[1]=(half_t)a0.y; h[2]=(half_t)a0.z; h[3]=(half_t)a0.w;
  h[4]=(half_t)a1.x; h[5]=(half_t)a1.y; h[6]=(half_t)a1.z; h[7]=(half_t)a1.w;
  *(half8*)(xh + base) = h;
  float4 q0 = ((const float4*)(wq + l * 8))[0], q1 = ((const float4*)(wq + l * 8))[1];
  float4 k0 = ((const float4*)(wk + l * 8))[0], k1 = ((const float4*)(wk + l * 8))[1];
  float dq = a0.x*q0.x + a0.y*q0.y + a0.z*q0.z + a0.w*q0.w
           + a1.x*q1.x + a1.y*q1.y + a1.z*q1.z + a1.w*q1.w;
  float dk = a0.x*k0.x + a0.y*k0.y + a0.z*k0.z + a0.w*k0.w
           + a1.x*k1.x + a1.y*k1.y + a1.z*k1.z + a1.w*k1.w;
  #pragma unroll
  for (int o = 32; o; o >>= 1) { dq += __shfl_xor(dq, o); dk += __shfl_xor(dk, o); }
  if (l == 0) { qs[wid] = dq + qkb[0]; ks[wid] = dk + qkb[1]; }
}

// ---------------- KNN v3: LDS-staged dbuf, min-only pass1, insert-from-empty pass2 ----------
// L2-traffic floor fix: each BLOCK (not wave) streams the 256KB candidate set once per pass
// via double-buffered global_load_lds -> 0.52 GB L2 traffic (was 2.1 GB direct).
// Pass 1: per-lane min d2 VALUE only (1 v_min/cand/query; no index tracking -> low VGPR).
// Merge: bitonic sort of 64 lane-min values; wst = 16th smallest (upper bound on true 16th:
//        the 16 smallest lane-mins are 16 distinct candidates with d <= wst).
// Pass 2: every candidate with d2 <= wst (expected ~18/query) is serially rank-inserted into
//        an initially-EMPTY sorted list (lex (d2,idx), r==16 reject). Each candidate appears
//        exactly once in the stream -> no dedup needed. wst tightens as the list fills.
// d2 arithmetic bit-identical to validated r1-r8 stream.
#define QPW 4
#define KTILE 512
__global__ __launch_bounds__(256, 4) void kknn(const float4* __restrict__ xw,
                                               const float4* __restrict__ xw2,
                                               int* __restrict__ idxo) {
  __shared__ __align__(16) float4 ldsA[2][KTILE];
  __shared__ __align__(16) float4 ldsB[2][KTILE];
  const int tid = threadIdx.x;
  const int l = tid & 63;
  const int w = tid >> 6;
  const int b = blockIdx.x >> 9;
  const int qbase = (blockIdx.x & 511) * (4 * QPW) + w * QPW;
  const float4* xb  = xw  + (size_t)b * NN;
  const float4* xa2 = xw2 + (size_t)b * NN;         // A pairs (x0,x1,y0,y1)
  const float4* xb2 = xa2 + NN / 2;                 // B pairs (z0,z1,sq0,sq1)

#define STAGE(t, bi) do {                                                        \
    int ts_ = (t) * KTILE;                                                       \
    gload16(xa2 + ts_ +       w * 64 + l, (void*)&ldsA[bi][      w * 64]);       \
    gload16(xa2 + ts_ + 256 + w * 64 + l, (void*)&ldsA[bi][256 + w * 64]);       \
    gload16(xb2 + ts_ +       w * 64 + l, (void*)&ldsB[bi][      w * 64]);       \
    gload16(xb2 + ts_ + 256 + w * 64 + l, (void*)&ldsB[bi][256 + w * 64]);       \
  } while (0)

  // loop-invariant packed (splatted) query operands
  f32x2 qxx[QPW], qyy[QPW], qzz[QPW], qww[QPW];
  #pragma unroll
  for (int qi = 0; qi < QPW; ++qi) {
    float4 qp = xb[qbase + qi];
    qxx[qi] = (f32x2){qp.x, qp.x};
    qyy[qi] = (f32x2){qp.y, qp.y};
    qzz[qi] = (f32x2){qp.z, qp.z};
    qww[qi] = (f32x2){qp.w, qp.w};
  }
  const f32x2 m2 = (f32x2){-2.0f, -2.0f};

  // ---- pass 1: per-lane packed min (values only) ----
  f32x2 mind[QPW];
  #pragma unroll
  for (int qi = 0; qi < QPW; ++qi) mind[qi] = (f32x2){__builtin_inff(), __builtin_inff()};

  STAGE(0, 0);
  __syncthreads();
  for (int t = 0; t < 8; ++t) {
    if (t < 7) STAGE(t + 1, (t + 1) & 1);
    #pragma unroll
    for (int it = 0; it < 8; ++it) {
      int p = it * 64 + l;
      float4 A  = ldsA[t & 1][p];
      float4 Bv = ldsB[t & 1][p];
      f32x2 cx = (f32x2){A.x, A.y};
      f32x2 cy = (f32x2){A.z, A.w};
      f32x2 cz = (f32x2){Bv.x, Bv.y};
      f32x2 cw = (f32x2){Bv.z, Bv.w};
      #pragma unroll
      for (int qi = 0; qi < QPW; ++qi) {
        f32x2 dot = __builtin_elementwise_fma(qzz[qi], cz,
                      __builtin_elementwise_fma(qyy[qi], cy, qxx[qi] * cx));
        f32x2 s2 = qww[qi] + cw;
        f32x2 d2 = __builtin_elementwise_fma(m2, dot, s2);
        mind[qi] = __builtin_elementwise_min(mind[qi], d2);
      }
    }
    __syncthreads();                                 // drains next-tile stage + sync readers
  }

  // ---- merge: bitonic sort 64 lane-min values; wst = 16th smallest ----
  float wst[QPW];
  #pragma unroll
  for (int qi = 0; qi < QPW; ++qi) {
    float d = fminf(mind[qi][0], mind[qi][1]);
    #pragma unroll
    for (int k = 2; k <= 64; k <<= 1) {
      #pragma unroll
      for (int j = k >> 1; j > 0; j >>= 1) {
        float od = __shfl_xor(d, j);
        bool up = ((l & k) == 0);
        bool lower_lane = ((l & j) == 0);
        bool oless = od < d;
        bool take = (up == lower_lane) ? oless : !oless;
        if (take) d = od;
      }
    }
    wst[qi] = __shfl(d, 15);
  }

  // ---- pass 2: insert all candidates with d2 <= wst into empty list ----
  float kd[QPW]; int ki[QPW];
  #pragma unroll
  for (int qi = 0; qi < QPW; ++qi) { kd[qi] = __builtin_inff(); ki[qi] = 0x7fffffff; }

  auto insert = [&](bool ok, float dv, int iv, int qi) {
    unsigned long long m = __ballot(ok);
    while (m) {
      int a = __builtin_ctzll(m);
      m &= m - 1;
      float dc = __shfl(dv, a);
      int ic = __shfl(iv, a);
      bool lower = (kd[qi] < dc) || (kd[qi] == dc && ki[qi] < ic);
      int r = __popcll(__ballot(lower) & 0xFFFFull);
      if (r < 16) {
        float pd = __shfl_up(kd[qi], 1, 16);
        int pi = __shfl_up(ki[qi], 1, 16);
        int pp = l & 15;
        if (pp == r)      { kd[qi] = dc; ki[qi] = ic; }
        else if (pp > r)  { kd[qi] = pd; ki[qi] = pi; }
        wst[qi] = fminf(wst[qi], __shfl(kd[qi], 15, 16));   // tighten once list fills
      }
    }
  };

  __syncthreads();
  STAGE(0, 0);
  __syncthreads();
  for (int t = 0; t < 8; ++t) {
    if (t < 7) STAGE(t + 1, (t + 1) & 1);
    #pragma unroll 2
    for (int it = 0; it < 8; ++it) {
      int p = it * 64 + l;
      float4 A  = ldsA[t & 1][p];
      float4 Bv = ldsB[t & 1][p];
      f32x2 cx = (f32x2){A.x, A.y};
      f32x2 cy = (f32x2){A.z, A.w};
      f32x2 cz = (f32x2){Bv.x, Bv.y};
      f32x2 cw = (f32x2){Bv.z, Bv.w};
      int ci0 = (t * KTILE + p) * 2;
      #pragma unroll
      for (int qi = 0; qi < QPW; ++qi) {
        f32x2 dot = __builtin_elementwise_fma(qzz[qi], cz,
                      __builtin_elementwise_fma(qyy[qi], cy, qxx[qi] * cx));
        f32x2 s2 = qww[qi] + cw;
        f32x2 d2 = __builtin_elementwise_fma(m2, dot, s2);
        bool ok0 = d2[0] <= wst[qi];
        bool ok1 = d2[1] <= wst[qi];
        if (__ballot(ok0 || ok1)) {                  // pre-screen: one ballot per pair
          insert(ok0, d2[0], ci0, qi);
          insert(ok1, d2[1], ci0 + 1, qi);
        }
      }
    }
    __syncthreads();
  }

  if (l < 16) {
    #pragma unroll
    for (int qi = 0; qi < QPW; ++qi)
      idxo[((size_t)b * NN + qbase + qi) * NKNN + l] = ki[qi];
  }
#undef STAGE
}

// ---------------- fp16 MFMA GEMM: C[M=..,512] = A[M,512] @ Bw[512,512]^T ----------------
template <int EPI>   // 0: store half(acc+bias) ; 1: store float(acc+bias+resid)
__global__ __launch_bounds__(256) void kgemm(const half_t* __restrict__ A,
                                             const half_t* __restrict__ Bw,
                                             const float* __restrict__ bias,
                                             const float* __restrict__ resid,
                                             void* __restrict__ Cout) {
  __shared__ __align__(16) half_t As[128 * 64];
  __shared__ __align__(16) half_t Bs[128 * 64];
  const int tid = threadIdx.x;
  const int l = tid & 63;
  const int w = tid >> 6;
  const int wm = w >> 1, wn = w & 1;
  const int mt = blockIdx.x >> 2;
  const int nt = blockIdx.x & 3;
  const int lr = l & 15, lg = l >> 4;

  f32x4 acc[4][4];
  #pragma unroll
  for (int i = 0; i < 4; ++i)
    #pragma unroll
    for (int j = 0; j < 4; ++j) acc[i][j] = (f32x4){0.f, 0.f, 0.f, 0.f};

  for (int kt = 0; kt < 8; ++kt) {
    #pragma unroll
    for (int i = 0; i < 4; ++i) {
      int id = i * 256 + tid;
      int rr = id >> 3, cc = id & 7;
      gload16(A + (size_t)(mt * 128 + rr) * ND + kt * 64 + cc * 8,
              (void*)(As + (size_t)(i * 256 + w * 64) * 8));
      gload16(Bw + (size_t)(nt * 128 + rr) * ND + kt * 64 + cc * 8,
              (void*)(Bs + (size_t)(i * 256 + w * 64) * 8));
    }
    __syncthreads();
    #pragma unroll
    for (int kk = 0; kk < 2; ++kk) {
      half8 af[4], bf[4];
      #pragma unroll
      for (int mi = 0; mi < 4; ++mi)
        af[mi] = *(const half8*)(As + (wm * 64 + mi * 16 + lr) * 64 + kk * 32 + lg * 8);
      #pragma unroll
      for (int ni = 0; ni < 4; ++ni)
        bf[ni] = *(const half8*)(Bs + (wn * 64 + ni * 16 + lr) * 64 + kk * 32 + lg * 8);
      #pragma unroll
      for (int mi = 0; mi < 4; ++mi)
        #pragma unroll
        for (int ni = 0; ni < 4; ++ni)
          acc[mi][ni] = __builtin_amdgcn_mfma_f32_16x16x32_f16(af[mi], bf[ni], acc[mi][ni], 0, 0, 0);
    }
    __syncthreads();
  }

  #pragma unroll
  for (int mi = 0; mi < 4; ++mi) {
    #pragma unroll
    for (int ni = 0; ni < 4; ++ni) {
      int col = nt * 128 + wn * 64 + ni * 16 + lr;
      #pragma unroll
      for (int r4 = 0; r4 < 4; ++r4) {
        size_t row = (size_t)mt * 128 + wm * 64 + mi * 16 + lg * 4 + r4;
        float v = acc[mi][ni][r4] + bias[col];
        if (EPI == 0) ((half_t*)Cout)[row * ND + col] = (half_t)v;
        else          ((float*)Cout)[row * ND + col] = v + resid[row * ND + col];
      }
    }
  }
}

// ---------------- attention: logits -> softmax -> weighted v gather ----------------
__global__ __launch_bounds__(256) void kattn(const int* __restrict__ idx,
                                             const float* __restrict__ qs,
                                             const float* __restrict__ ks,
                                             const half_t* __restrict__ vh,
                                             half_t* __restrict__ xoh) {
  int wid = blockIdx.x * 4 + (threadIdx.x >> 6);
  int l = threadIdx.x & 63;
  int b = wid >> 13;
  int j = l & 15;
  int nb = idx[(size_t)wid * NKNN + j];
  float ksv = ks[(size_t)b * NN + nb];
  float logit = __fdiv_rn(__fmul_rn(qs[wid], ksv), 22.627416997969522f); // /sqrt(512)
  float mx = logit;
  #pragma unroll
  for (int o = 8; o; o >>= 1) mx = fmaxf(mx, __shfl_xor(mx, o, 16));
  float e = expf(logit - mx);
  float s = e;
  #pragma unroll
  for (int o = 8; o; o >>= 1) s += __shfl_xor(s, o, 16);
  float p = e / s;

  float acc[8] = {0.f, 0.f, 0.f, 0.f, 0.f, 0.f, 0.f, 0.f};
  #pragma unroll
  for (int t16 = 0; t16 < 16; ++t16) {
    float wj = __shfl(p, t16, 16);
    int ij = __shfl(nb, t16, 16);
    const half8 vv = *(const half8*)(vh + ((size_t)b * NN + ij) * ND + l * 8);
    #pragma unroll
    for (int u = 0; u < 8; ++u) acc[u] += wj * (float)vv[u];
  }
  half8 ho;
  #pragma unroll
  for (int u = 0; u < 8; ++u) ho[u] = (half_t)acc[u];
  *(half8*)(xoh + (size_t)wid * ND + l * 8) = ho;
}

// ---------------- launcher ----------------
extern "C" void kernel_launch(void* const* d_in, const int* in_sizes, int n_in,
                              void* d_out, int out_size, void* d_ws, size_t ws_size,
                              hipStream_t stream) {
  const float* x    = (const float*)d_in[0];
  const float* xyz  = (const float*)d_in[1];
  const float* wqkv = (const float*)d_in[2];
  const float* bqkv = (const float*)d_in[3];
  const float* wfc  = (const float*)d_in[4];
  const float* bfc  = (const float*)d_in[5];
  char* ws = (char*)d_ws;
  half_t* xh   = (half_t*)(ws + OFF_XH);
  half_t* vh   = (half_t*)(ws + OFF_VH);
  half_t* xoh  = (half_t*)(ws + OFF_XOH);
  half_t* wvh  = (half_t*)(ws + OFF_WVH);
  half_t* wfch = (half_t*)(ws + OFF_WFCH);
  float4* xw   = (float4*)(ws + OFF_XW);
  float4* xw2  = (float4*)(ws + OFF_XW2);
  int*    idx  = (int*)(ws + OFF_IDX);
  float*  wqc  = (float*)(ws + OFF_WQC);
  float*  wkc  = (float*)(ws + OFF_WKC);
  float*  qkb  = (float*)(ws + OFF_QKB);
  float*  qs   = (float*)(ws + OFF_QS);
  float*  ks   = (float*)(ws + OFF_KS);

  ksetup<<<dim3(305), dim3(256), 0, stream>>>(wqkv, bqkv, wfc, xyz,
                                              wqc, wkc, qkb, wvh, wfch, xw, xw2);
  kxh   <<<dim3(4096),dim3(256), 0, stream>>>(x, wqc, wkc, qkb, xh, qs, ks);
  kknn  <<<dim3(1024),dim3(256), 0, stream>>>(xw, xw2, idx);
  kgemm<0><<<dim3(512),dim3(256), 0, stream>>>(xh, wvh, bqkv + 1024, (const float*)nullptr, (void*)vh);
  kattn <<<dim3(4096),dim3(256), 0, stream>>>(idx, qs, ks, vh, xoh);
  kgemm<1><<<dim3(512),dim3(256), 0, stream>>>(xoh, wfch, bfc, x, d_out);
}